// Round 1
// baseline (77.752 us; speedup 1.0000x reference)
//
#include <hip/hip_runtime.h>

// All-pairs edge MLP, N_E=1024, NIN=64, HID=128, OUT=64, fp32.
// out[i] = ((1/1023) * sum_{k!=i} tanh(A[i]+B[k])) @ W2 + b2
//   A = x@W1[:64,:],  B = x@W1[64:,:] + b1
// Rank-separated tanh via 2D Chebyshev (P=30, domain [-5.5,5.5]^2):
//   sum_k tanh(a_i+b_k) = sum_p T_p(a_i) V_p[h],  V = C @ M,
//   M_q[h] = sum_k T_q(b_k[h]).
//
// R5: dispatch-count attack. Evidence: all 4 compute kernels are < 39 us
// (absent from rocprof top-5; only 256MiB poison fills show), while the op's
// roofline is ~1-2 us -> time is dispatch/latency-structural, not BW/FLOP.
//  - moments fused into prep: T_q computed from accB REGISTERS (B never
//    re-read), LDS-reduced per block, atomicAdd into 4-replicated M4
//    (64-way contention per address == old K2's proven level).
//  - M4 zeroed by a 60KB hipMemsetAsync (graph-capturable) instead of a
//    kernel, since prep now atomics into it.
//  - v_kernel folded into combine: each block recomputes V=C@(sum M4) in
//    LDS (~115 KFLOP, ~1us total) -- cheaper than a dispatch + V round-trip.
// Pipeline: memsetAsync(M4) -> prep_kernel -> combine_kernel  (3 dispatches).

#define N_E  1024
#define NIN  64
#define HID  128
#define OUTD 64
#define PCH  30      // Chebyshev terms per variable
#define NQ   32      // DCT-I grid: NQ+1 Lobatto points
#define S_CH 5.5f
#define NCOPY 4      // replicated moment buffers (contention /4)

static constexpr float INV_S     = 1.0f / 5.5f;
static constexpr float TWO_LOG2E = 2.8853900817779268f; // 2*log2(e)
static constexpr float PI_F      = 3.14159265358979323846f;

__device__ __forceinline__ float tanh_fast(float u) {
  // tanh(u) = 1 - 2/(1+exp2(u*2log2e))
  return 1.0f - 2.0f * __builtin_amdgcn_rcpf(
      1.0f + __builtin_amdgcn_exp2f(u * TWO_LOG2E));
}

// ---- K1: blocks 0..255 compute A,B for 4 rows each AND the Chebyshev
// moments of those rows from registers (atomicAdd into M4[blk&3]).
// Block 256 computes the PCH x PCH coefficient matrix C (fp32 DCT-I).
__global__ __launch_bounds__(256) void prep_kernel(
    const float* __restrict__ x, const float* __restrict__ W1,
    const float* __restrict__ b1,
    float* __restrict__ A, float* __restrict__ B,
    float* __restrict__ C, float* __restrict__ M4) {
  const int t = threadIdx.x;
  if (blockIdx.x < N_E / 4) {
    __shared__ float xs[4][NIN];
    __shared__ float Msub[PCH][256];
    const int h = t & (HID - 1), sub = t >> 7;      // sub in {0,1}
    const int r0 = blockIdx.x * 4 + sub * 2;        // this thread: rows r0, r0+1
    // stage 4 rows of x (256 floats, one per thread)
    xs[t >> 6][t & 63] = x[(blockIdx.x * 4 + (t >> 6)) * NIN + (t & 63)];
    __syncthreads();
    float aA0 = 0.f, aA1 = 0.f, aB0 = 0.f, aB1 = 0.f;
    #pragma unroll 8
    for (int f = 0; f < NIN; ++f) {
      const float wa = W1[f * HID + h];             // coalesced over h, reused x2 rows
      const float wb = W1[(NIN + f) * HID + h];
      const float x0 = xs[sub * 2][f], x1 = xs[sub * 2 + 1][f];  // wave-broadcast
      aA0 += x0 * wa; aA1 += x1 * wa;
      aB0 += x0 * wb; aB1 += x1 * wb;
    }
    const float bb = b1[h];
    const float B0 = aB0 + bb, B1 = aB1 + bb;
    A[r0 * HID + h] = aA0; A[(r0 + 1) * HID + h] = aA1;
    B[r0 * HID + h] = B0;  B[(r0 + 1) * HID + h] = B1;
    // Chebyshev moments of rows r0,r0+1 straight from registers
    const float c0v = fminf(fmaxf(B0, -S_CH), S_CH) * INV_S;
    const float c1v = fminf(fmaxf(B1, -S_CH), S_CH) * INV_S;
    float m[PCH];
    m[0] = 2.f; m[1] = c0v + c1v;
    float u0 = 1.f, u1 = c0v, v0 = 1.f, v1 = c1v;
    const float u2x = c0v + c0v, v2x = c1v + c1v;
    #pragma unroll
    for (int q = 2; q < PCH; ++q) {
      const float u2 = u2x * u1 - u0, v2 = v2x * v1 - v0;
      m[q] = u2 + v2;
      u0 = u1; u1 = u2; v0 = v1; v1 = v2;
    }
    #pragma unroll
    for (int q = 0; q < PCH; ++q) Msub[q][t] = m[q];
    __syncthreads();
    const int cpy = (blockIdx.x & (NCOPY - 1)) * (PCH * HID);
    for (int idx = t; idx < PCH * HID; idx += 256) {
      const int q = idx >> 7, hh = idx & (HID - 1);
      atomicAdd(&M4[cpy + idx], Msub[q][hh] + Msub[q][hh + HID]);
    }
  } else {
    // ---- fp32 Chebyshev coefficient matrix C[p][q] via DCT-I ----
    __shared__ float ctab[NQ + 1];
    __shared__ float fg[(NQ + 1) * (NQ + 2)];  // [j][l], padded row stride
    __shared__ float G[PCH * (NQ + 2)];        // [q][j], padded row stride
    if (t <= NQ) ctab[t] = cosf((float)t * (PI_F / (float)NQ));
    __syncthreads();
    for (int idx = t; idx < (NQ + 1) * (NQ + 1); idx += 256) {
      const int j = idx / (NQ + 1), l = idx % (NQ + 1);
      fg[j * (NQ + 2) + l] = tanh_fast(S_CH * (ctab[j] + ctab[l]));
    }
    __syncthreads();
    // G[q][j] = sum_l w_l fg[j][l] cos(q l pi/NQ)  (cos via recurrence)
    for (int idx = t; idx < PCH * (NQ + 1); idx += 256) {
      const int q = idx / (NQ + 1), j = idx % (NQ + 1);
      const float cphi = ctab[q];
      float c0 = 1.f, c1 = cphi;
      float s = 0.5f * fg[j * (NQ + 2) + 0];   // l=0: w=1/2, cos=1
      for (int l = 1; l <= NQ; ++l) {
        const float w = (l == NQ) ? 0.5f : 1.0f;
        s += w * fg[j * (NQ + 2) + l] * c1;
        const float c2 = 2.f * cphi * c1 - c0; c0 = c1; c1 = c2;
      }
      G[q * (NQ + 2) + j] = s;
    }
    __syncthreads();
    // C[p][q] = cp cq sum_j w_j G[q][j] cos(p j pi/NQ)
    for (int idx = t; idx < PCH * PCH; idx += 256) {
      const int p = idx / PCH, q = idx % PCH;
      const float cphi = ctab[p];
      float c0 = 1.f, c1 = cphi;
      float s = 0.5f * G[q * (NQ + 2) + 0];
      for (int j = 1; j <= NQ; ++j) {
        const float w = (j == NQ) ? 0.5f : 1.0f;
        s += w * G[q * (NQ + 2) + j] * c1;
        const float c2 = 2.f * cphi * c1 - c0; c0 = c1; c1 = c2;
      }
      const float cp = (p == 0 ? 1.f : 2.f) / (float)NQ;
      const float cq = (q == 0 ? 1.f : 2.f) / (float)NQ;
      C[p * PCH + q] = s * cp * cq;
    }
  }
}

// ---- K2: per block (4 rows): stage C + Msum, recompute V=C@M in LDS,
// then S[i,h] = (sum_p T_p(a_i) V_p[h] - tanh(A+B))/1023 and out = S@W2+b2.
__global__ __launch_bounds__(512) void combine_kernel(
    const float* __restrict__ A, const float* __restrict__ B,
    const float* __restrict__ M4, const float* __restrict__ C,
    const float* __restrict__ W2, const float* __restrict__ b2,
    float* __restrict__ out) {
  __shared__ float Cs[PCH * PCH];        // 3.6 KB
  __shared__ float Ms[PCH * HID];        // 15 KB
  __shared__ float Vl[PCH * HID];        // 15 KB
  __shared__ float Sl[4][HID];
  __shared__ float red[4][2][OUTD];
  const int t = threadIdx.x;
  for (int idx = t; idx < PCH * PCH; idx += 512) Cs[idx] = C[idx];
  for (int idx = t; idx < PCH * HID; idx += 512)
    Ms[idx] = M4[idx] + M4[PCH * HID + idx] +
              M4[2 * PCH * HID + idx] + M4[3 * PCH * HID + idx];
  __syncthreads();
  // V = C @ Msum, entirely in LDS (redundant per block; ~115 KFLOP)
  for (int idx = t; idx < PCH * HID; idx += 512) {
    const int p = idx >> 7, hh = idx & (HID - 1);
    float acc = 0.f;
    #pragma unroll
    for (int q = 0; q < PCH; ++q) acc += Cs[p * PCH + q] * Ms[q * HID + hh];
    Vl[idx] = acc;                       // Cs broadcast, Ms stride-1: conflict-free
  }
  __syncthreads();
  const int h = t & (HID - 1), row = t >> 7;
  const int i = blockIdx.x * 4 + row;
  const float ar = A[i * HID + h], br = B[i * HID + h];
  const float a = fminf(fmaxf(ar, -S_CH), S_CH) * INV_S;
  float t0 = 1.f, t1 = a;
  const float a2x = a + a;
  float acc = Vl[h] + a * Vl[HID + h];
  #pragma unroll
  for (int p = 2; p < PCH; ++p) {
    const float t2 = a2x * t1 - t0;
    acc += t2 * Vl[p * HID + h];
    t0 = t1; t1 = t2;
  }
  const float ts = tanh_fast(ar + br);   // exact self term (k==i)
  Sl[row][h] = (acc - ts) * (1.f / (float)(N_E - 1));
  __syncthreads();
  const int o = t & (OUTD - 1), half = (t >> 6) & 1, r2 = t >> 7;
  const int h0 = half * 64;
  float po = 0.f;
  #pragma unroll 16
  for (int hh = 0; hh < 64; ++hh)
    po += Sl[r2][h0 + hh] * W2[(h0 + hh) * OUTD + o];   // coalesced over o, L1-hot
  red[r2][half][o] = po;
  __syncthreads();
  if (t < 4 * OUTD) {
    const int rr = t >> 6, oo = t & (OUTD - 1);
    out[(blockIdx.x * 4 + rr) * OUTD + oo] = red[rr][0][oo] + red[rr][1][oo] + b2[oo];
  }
}

extern "C" void kernel_launch(void* const* d_in, const int* in_sizes, int n_in,
                              void* d_out, int out_size, void* d_ws, size_t ws_size,
                              hipStream_t stream) {
  const float* x  = (const float*)d_in[0];
  const float* W1 = (const float*)d_in[1];
  const float* b1 = (const float*)d_in[2];
  const float* W2 = (const float*)d_in[3];
  const float* b2 = (const float*)d_in[4];
  float* out = (float*)d_out;

  float* A  = (float*)d_ws;            // [N_E][HID]
  float* B  = A + N_E * HID;           // [N_E][HID]
  float* M4 = B + N_E * HID;           // [NCOPY][PCH][HID]
  float* C  = M4 + NCOPY * PCH * HID;  // [PCH][PCH]

  hipMemsetAsync((void*)M4, 0, NCOPY * PCH * HID * sizeof(float), stream);
  prep_kernel<<<N_E / 4 + 1, 256, 0, stream>>>(x, W1, b1, A, B, C, M4);
  combine_kernel<<<N_E / 4, 512, 0, stream>>>(A, B, M4, C, W2, b2, out);
}